// Round 4
// baseline (153.085 us; speedup 1.0000x reference)
//
#include <hip/hip_runtime.h>

// Depthwise 5x5 SAME conv + gate residual: out = x*(alpha*conv + bias) + x
// x: (B=32, H=112, W=112, C=96) f32 NHWC. kernel: (5,5,96) f32.
//
// R4 change vs R3 (latency-bound: T_iter ~1250 cyc, gated on ~900-cyc HBM
// first-touch latency with prefetch depth 1):
//  - Prefetch depth 3: triple row-buffer (ta/tb/tc) + unroll-by-3. Each
//    row's 5 tap loads are issued 3 bodies before the FMAs that consume
//    them -> T_iter >= Lat/3 ~ 300 cyc, issue-supply ~450 cyc -> BW-bound.
//  - H-edge handling moved to a wave-uniform branch around the row load
//    (chunk/row index is uniform across a wave) instead of per-tap masks.
//  - All chunks run constant NIT=42 iterations; store is range-guarded.

#define CH 96
#define WI 112
#define HI 112
#define BATCH 32
#define NSPLIT 3
#define CHUNK_ROWS 38               // chunks: 38, 38, 36
#define NIT 42                      // CHUNK_ROWS + 4, constant trip count
#define ROW_STRIDE (WI * CH)        // 10752
#define IMG_STRIDE (HI * WI * CH)   // 1204224

__global__ __launch_bounds__(256, 6) void dwconv_gate_kernel(
    const float* __restrict__ x,
    const float* __restrict__ kern,
    const float* __restrict__ alpha,
    const float* __restrict__ bias,
    float* __restrict__ out)
{
    const int gid = blockIdx.x * blockDim.x + threadIdx.x;
    // gid -> (b, chunk, w, c); c innermost for coalescing
    const int c     = gid % CH;
    const int r1    = gid / CH;
    const int w     = r1 % WI;
    const int r2    = r1 / WI;
    const int chunk = r2 % NSPLIT;
    const int b     = r2 / NSPLIT;
    if (b >= BATCH) return;

    const float alphav = alpha[0];
    const float biasv  = bias[0];

    // Per-channel 5x5 weights in registers (statically indexed).
    float wt[25];
#pragma unroll
    for (int i = 0; i < 25; ++i) wt[i] = kern[i * CH + c];

    // Loop-invariant width-edge masks.
    bool mok[5];
#pragma unroll
    for (int dx = 0; dx < 5; ++dx) {
        const int ww = w + dx - 2;
        mok[dx] = (ww >= 0) && (ww < WI);
    }

    const int h0   = chunk * CHUNK_ROWS;
    const int rows = (chunk == NSPLIT - 1) ? (HI - h0) : CHUNK_ROWS; // 38/38/36

    const float* px = x   + (size_t)b * IMG_STRIDE + (size_t)w * CH + c;
    float*       po = out + (size_t)b * IMG_STRIDE + (size_t)w * CH + c;

    // acc0 holds the oldest (next-to-complete) output row's partial sum.
    float acc0 = 0.f, acc1 = 0.f, acc2 = 0.f, acc3 = 0.f, acc4 = 0.f;
    float xp1 = 0.f, xp2 = 0.f;   // center-tap history (delay 2) for residual

    float ta[5], tb[5], tc[5];

    // Row load: row index is wave-uniform (chunk spans 168 waves), so the
    // OOB check is a cheap uniform branch; in-range rows load 5 taps with
    // compile-time immediate offsets.
#define LOADROW(BUF, RIN) do {                                         \
        const int _r = (RIN);                                          \
        if ((unsigned)_r < (unsigned)HI) {                             \
            const float* _p = px + (ptrdiff_t)_r * ROW_STRIDE;         \
            BUF[0] = mok[0] ? _p[-2 * CH] : 0.f;                       \
            BUF[1] = mok[1] ? _p[-1 * CH] : 0.f;                       \
            BUF[2] = _p[0];                                            \
            BUF[3] = mok[3] ? _p[ 1 * CH] : 0.f;                       \
            BUF[4] = mok[4] ? _p[ 2 * CH] : 0.f;                       \
        } else {                                                       \
            BUF[0] = 0.f; BUF[1] = 0.f; BUF[2] = 0.f;                  \
            BUF[3] = 0.f; BUF[4] = 0.f;                                \
        }                                                              \
    } while (0)

    // Prologue: 15 loads in flight before the first consume.
    LOADROW(ta, h0 - 2);
    LOADROW(tb, h0 - 1);
    LOADROW(tc, h0    );

    // Body I consumes input row (h0-2+I), then reissues its buffer for row
    // (h0+1+I), consumed 3 bodies later (prefetch depth 3).
#define BODY(I, T) do {                                                \
        const int _i = (I);                                            \
        _Pragma("unroll")                                              \
        for (int dx = 0; dx < 5; ++dx) {                               \
            acc0 = fmaf(T[dx], wt[20 + dx], acc0);                     \
            acc1 = fmaf(T[dx], wt[15 + dx], acc1);                     \
            acc2 = fmaf(T[dx], wt[10 + dx], acc2);                     \
            acc3 = fmaf(T[dx], wt[ 5 + dx], acc3);                     \
            acc4 = fmaf(T[dx], wt[ 0 + dx], acc4);                     \
        }                                                              \
        if (_i >= 4 && _i - 4 < rows) {                                \
            const float g = fmaf(acc0, alphav, biasv);                 \
            po[(ptrdiff_t)(h0 - 4 + _i) * ROW_STRIDE] = fmaf(g, xp2, xp2); \
        }                                                              \
        xp2 = xp1; xp1 = T[2];                                         \
        acc0 = acc1; acc1 = acc2; acc2 = acc3; acc3 = acc4; acc4 = 0.f;\
        LOADROW(T, h0 + 1 + _i);                                       \
    } while (0)

    for (int i = 0; i < NIT; i += 3) {
        BODY(i + 0, ta);
        BODY(i + 1, tb);
        BODY(i + 2, tc);
    }
#undef BODY
#undef LOADROW
}

extern "C" void kernel_launch(void* const* d_in, const int* in_sizes, int n_in,
                              void* d_out, int out_size, void* d_ws, size_t ws_size,
                              hipStream_t stream) {
    const float* x     = (const float*)d_in[0];
    const float* kern  = (const float*)d_in[1];
    const float* alpha = (const float*)d_in[2];
    const float* bias  = (const float*)d_in[3];
    float* out = (float*)d_out;

    const int total = BATCH * NSPLIT * WI * CH;   // 1,032,192 = 4032 * 256
    dim3 block(256);
    dim3 grid(total / 256);                       // 4032 blocks
    hipLaunchKernelGGL(dwconv_gate_kernel, grid, block, 0, stream,
                       x, kern, alpha, bias, out);
}

// Round 5
// 102.403 us; speedup vs baseline: 1.4949x; 1.4949x over previous
//
#include <hip/hip_runtime.h>

// Depthwise 5x5 SAME conv + gate residual: out = x*(alpha*conv + bias) + x
// x: (B=32, H=112, W=112, C=96) f32 NHWC. kernel: (5,5,96) f32.
//
// R5 vs R3/R4: attack DRAM efficiency + instruction count.
//  - float2 channel pairs (c2 innermost): every tap load / store is 512 B
//    contiguous per wave (vs 256 B scalar). Halves waves and insts/output.
//  - Weight-zeroing for W-edges: tap addresses clamped to [0,W) once,
//    OOB columns' WEIGHTS zeroed at init -> no per-iteration masking.
//  - Ping-pong 2-row-buffer prefetch (depth 1, no copies) - R3's scheme
//    without R4's macro/triple-buffer pathology.
//  - NSPLIT=3, __launch_bounds__(256,4): 2016 blocks, 4 resident blocks/CU
//    -> 1.97 rounds, 98.4% packing; VGPR cap 128 (live set ~100, no spill).

#define CH     96
#define C2     48                  // float2 channel-pairs per position
#define WI     112
#define HI     112
#define BATCH  32
#define NSPLIT 3
#define CHUNK_ROWS 38              // chunks: 38, 38, 36 (nit 42/42/40, even)
#define ROW_F2 (WI * C2)           // float2 per image row = 5376
#define IMG_F2 (HI * ROW_F2)

__global__ __launch_bounds__(256, 4) void dwconv_gate_kernel(
    const float* __restrict__ x,
    const float* __restrict__ kern,
    const float* __restrict__ alpha,
    const float* __restrict__ bias,
    float* __restrict__ out)
{
    const int gid = blockIdx.x * blockDim.x + threadIdx.x;
    // gid -> (b, chunk, w, c2); c2 innermost for coalescing
    const int c2    = gid % C2;
    const int r1    = gid / C2;
    const int w     = r1 % WI;
    const int r2    = r1 / WI;
    const int chunk = r2 % NSPLIT;
    const int b     = r2 / NSPLIT;
    if (b >= BATCH) return;

    const float alphav = alpha[0];
    const float biasv  = bias[0];

    // Clamped tap offsets (float2 units). OOB taps point at a valid column;
    // their contribution is killed by zeroed weights below.
    int toff[5];
    bool mok[5];
#pragma unroll
    for (int dx = 0; dx < 5; ++dx) {
        const int ww = w + dx - 2;
        mok[dx] = (ww >= 0) && (ww < WI);
        const int wc = ww < 0 ? 0 : (ww >= WI ? WI - 1 : ww);
        toff[dx] = (wc - w) * C2;
    }

    // Per-channel-pair 5x5 weights; W-edge columns zeroed once.
    float2 wt[25];
#pragma unroll
    for (int i = 0; i < 25; ++i) {
        float2 v = *(const float2*)(kern + i * CH + 2 * c2);
        if (!mok[i % 5]) v = make_float2(0.f, 0.f);
        wt[i] = v;
    }

    const int h0   = chunk * CHUNK_ROWS;
    const int rows = (chunk == NSPLIT - 1) ? (HI - h0) : CHUNK_ROWS;
    const int nit  = rows + 4;     // 42 / 42 / 40 (always even)

    const float2* px = (const float2*)x   + (size_t)b * IMG_F2 + (size_t)w * C2 + c2;
    float2*       po = (float2*)      out + (size_t)b * IMG_F2 + (size_t)w * C2 + c2;

    float2 acc0 = make_float2(0.f, 0.f), acc1 = acc0, acc2 = acc0,
           acc3 = acc0, acc4 = acc0;
    float2 xp1 = acc0, xp2 = acc0;   // center-tap history (delay 2)
    float2 ta[5], tb[5];

    // Preload input row h0-2 into ta.
    {
        const int r = h0 - 2;
        if (r >= 0) {                       // r < HI always holds here
            const float2* p = px + (ptrdiff_t)r * ROW_F2;
#pragma unroll
            for (int dx = 0; dx < 5; ++dx) ta[dx] = p[toff[dx]];
        } else {
#pragma unroll
            for (int dx = 0; dx < 5; ++dx) ta[dx] = make_float2(0.f, 0.f);
        }
    }

    // Body _i: prefetch row h0-1+_i into TLOAD, compute row h0-2+_i from
    // TCONS (loaded last body), emit output h0-4+_i once complete.
#define BODY(I, TCONS, TLOAD) do {                                         \
        const int _i = (I);                                                \
        const int _rn = h0 - 1 + _i;                                       \
        if ((unsigned)_rn < (unsigned)HI && _i + 1 < nit) {                \
            const float2* _p = px + (ptrdiff_t)_rn * ROW_F2;               \
            TLOAD[0] = _p[toff[0]];                                        \
            TLOAD[1] = _p[toff[1]];                                        \
            TLOAD[2] = _p[toff[2]];                                        \
            TLOAD[3] = _p[toff[3]];                                        \
            TLOAD[4] = _p[toff[4]];                                        \
        } else {                                                           \
            TLOAD[0] = make_float2(0.f, 0.f);                              \
            TLOAD[1] = make_float2(0.f, 0.f);                              \
            TLOAD[2] = make_float2(0.f, 0.f);                              \
            TLOAD[3] = make_float2(0.f, 0.f);                              \
            TLOAD[4] = make_float2(0.f, 0.f);                              \
        }                                                                  \
        _Pragma("unroll")                                                  \
        for (int dx = 0; dx < 5; ++dx) {                                   \
            acc0.x = fmaf(TCONS[dx].x, wt[20 + dx].x, acc0.x);             \
            acc0.y = fmaf(TCONS[dx].y, wt[20 + dx].y, acc0.y);             \
            acc1.x = fmaf(TCONS[dx].x, wt[15 + dx].x, acc1.x);             \
            acc1.y = fmaf(TCONS[dx].y, wt[15 + dx].y, acc1.y);             \
            acc2.x = fmaf(TCONS[dx].x, wt[10 + dx].x, acc2.x);             \
            acc2.y = fmaf(TCONS[dx].y, wt[10 + dx].y, acc2.y);             \
            acc3.x = fmaf(TCONS[dx].x, wt[ 5 + dx].x, acc3.x);             \
            acc3.y = fmaf(TCONS[dx].y, wt[ 5 + dx].y, acc3.y);             \
            acc4.x = fmaf(TCONS[dx].x, wt[ 0 + dx].x, acc4.x);             \
            acc4.y = fmaf(TCONS[dx].y, wt[ 0 + dx].y, acc4.y);             \
        }                                                                  \
        if (_i >= 4) {                      /* i-4 < rows holds: i < nit */\
            float2 o;                                                      \
            o.x = fmaf(fmaf(acc0.x, alphav, biasv), xp2.x, xp2.x);         \
            o.y = fmaf(fmaf(acc0.y, alphav, biasv), xp2.y, xp2.y);         \
            po[(ptrdiff_t)(h0 - 4 + _i) * ROW_F2] = o;                     \
        }                                                                  \
        xp2 = xp1; xp1 = TCONS[2];                                         \
        acc0 = acc1; acc1 = acc2; acc2 = acc3; acc3 = acc4;                \
        acc4 = make_float2(0.f, 0.f);                                      \
    } while (0)

    for (int i = 0; i < nit; i += 2) {
        BODY(i,     ta, tb);
        BODY(i + 1, tb, ta);
    }
#undef BODY
}

extern "C" void kernel_launch(void* const* d_in, const int* in_sizes, int n_in,
                              void* d_out, int out_size, void* d_ws, size_t ws_size,
                              hipStream_t stream) {
    const float* x     = (const float*)d_in[0];
    const float* kern  = (const float*)d_in[1];
    const float* alpha = (const float*)d_in[2];
    const float* bias  = (const float*)d_in[3];
    float* out = (float*)d_out;

    const int total = BATCH * NSPLIT * WI * C2;   // 516,096 = 2016 * 256
    dim3 block(256);
    dim3 grid(total / 256);                       // 2016 blocks, 8064 waves
    hipLaunchKernelGGL(dwconv_gate_kernel, grid, block, 0, stream,
                       x, kern, alpha, bias, out);
}